// Round 14
// baseline (131.851 us; speedup 1.0000x reference)
//
#include <hip/hip_runtime.h>

#define INV_SQRT2 0.70710678118654752440f
#define KH 0.35355339059327376220f   // INV_SQRT2 * 0.5 (output scale folded in)

// Stage-2 (first-stage) filter table as constexpr: compile-time indices after
// unroll -> coefficients fold to immediates; structural zeros kill 20% of FMAs.
constexpr float c_first[2][10][2] = {
  { { 0.00000000000000f,  0.00000000000000f},
    {-0.08838834764832f, -0.01122679215254f},
    { 0.08838834764832f,  0.01122679215254f},
    { 0.69587998903400f,  0.08838834764832f},
    { 0.69587998903400f,  0.08838834764832f},
    { 0.08838834764832f, -0.69587998903400f},
    {-0.08838834764832f,  0.69587998903400f},
    { 0.01122679215254f, -0.08838834764832f},
    { 0.01122679215254f, -0.08838834764832f},
    { 0.00000000000000f,  0.00000000000000f} },
  { { 0.01122679215254f,  0.00000000000000f},
    { 0.01122679215254f,  0.00000000000000f},
    {-0.08838834764832f, -0.08838834764832f},
    { 0.08838834764832f, -0.08838834764832f},
    { 0.69587998903400f,  0.69587998903400f},
    { 0.69587998903400f, -0.69587998903400f},
    { 0.08838834764832f,  0.08838834764832f},
    {-0.08838834764832f,  0.08838834764832f},
    { 0.00000000000000f,  0.01122679215254f},
    { 0.00000000000000f, -0.01122679215254f} }
};

// Stage-1 table stays __constant__: its [n]/[m] indices are runtime-uniform.
__constant__ float c_qshift[2][10][2] = {
  { { 0.03516384f,  0.00000000f},
    { 0.00000000f,  0.00000000f},
    {-0.08832942f, -0.11430184f},
    { 0.23389032f,  0.00000000f},
    { 0.76027237f,  0.58751830f},
    { 0.58751830f, -0.76027237f},
    { 0.00000000f,  0.23389032f},
    {-0.11430184f,  0.08832942f},
    { 0.00000000f,  0.00000000f},
    { 0.00000000f, -0.03516384f} },
  { { 0.00000000f, -0.03516384f},
    { 0.00000000f,  0.00000000f},
    {-0.11430184f,  0.08832942f},
    { 0.00000000f,  0.23389032f},
    { 0.58751830f, -0.76027237f},
    { 0.76027237f,  0.58751830f},
    { 0.23389032f,  0.00000000f},
    {-0.08832942f, -0.11430184f},
    { 0.00000000f,  0.00000000f},
    { 0.03516384f,  0.00000000f} }
};

// ---------------------------------------------------------------------------
// Stage 1: level-2 synthesis (Q-shift) — R9 exact form (proven ~23us):
// SEG=16, launch_bounds(128,3), gather + keep-alive pins.
// ---------------------------------------------------------------------------
__global__ __launch_bounds__(128, 3) void idtcwt_stage1(
    const float* __restrict__ lows, const float* __restrict__ highs1,
    float* __restrict__ lo2)
{
  constexpr int HIN = 128, WIN = 128, C = 3, B = 16;
  constexpr int ROWF  = WIN * C;        // 384 floats per input row
  constexpr int ROWO  = 2 * WIN * C;    // 768 floats per output row
  constexpr int PLANE = HIN * WIN * C;  // 49152
  constexpr int SEG   = 16;

  const int jj = blockIdx.x * 128 + threadIdx.x;  // 0..383 = (t, c)
  const int c  = jj % 3;
  const int t  = jj / 3;                // input column 0..127
  const int z  = blockIdx.z;            // combo*16 + b
  const int combo = z >> 4;
  const int b     = z & 15;
  const int m = combo >> 1, n = combo & 1;

  const float* lo = lows + (combo * B + b) * PLANE;
  const int pa = (m == n) ? 0 : 1;
  const int pb = (m == n) ? 3 : 2;
  const float sgn = (m == 0) ? 1.0f : -1.0f;
  const int bandStride = B * PLANE;     // 786432
  const float* hA = highs1 + (pa * 3 * B + b) * PLANE;
  const float* hB = highs1 + (pb * 3 * B + b) * PLANE;

  int wc3[5];
#pragma unroll
  for (int p = 0; p < 5; ++p) {
    int w = t + 2 - p;
    if (w >= WIN) w -= WIN;
    if (w < 0)  w += WIN;
    wc3[p] = w * C + c;
  }

  float lae[5], lao[5], hae[5], hao[5];
#pragma unroll
  for (int k = 0; k < 5; ++k) { lae[k]=0.f; lao[k]=0.f; hae[k]=0.f; hao[k]=0.f; }

  const int s0 = blockIdx.y * SEG;
  float* outp = lo2 + (combo * B + b) * (4 * PLANE);

#pragma unroll 1
  for (int ui = 0; ui < SEG + 4; ++ui) {
    const int u  = (s0 - 2 + ui) & (HIN - 1);
#pragma unroll
    for (int k = 0; k < 4; ++k) { lae[k]=lae[k+1]; lao[k]=lao[k+1]; hae[k]=hae[k+1]; hao[k]=hao[k+1]; }
    const int rb = u * ROWF;

    float rl[5], rA[3][5], rB[3][5];
#pragma unroll
    for (int p = 0; p < 5; ++p) {
      const int idx = rb + wc3[p];
      rl[p]    = lo[idx];
      rA[0][p] = hA[idx];
      rB[0][p] = hB[idx];
      rA[1][p] = hA[idx +   bandStride];
      rB[1][p] = hB[idx +   bandStride];
      rA[2][p] = hA[idx + 2*bandStride];
      rB[2][p] = hB[idx + 2*bandStride];
    }
    // keep-alive pins: forbid chunking of the 35-load batch
    asm volatile("" :: "v"(rl[0]),"v"(rl[1]),"v"(rl[2]),"v"(rl[3]),"v"(rl[4]),
                       "v"(rA[0][0]),"v"(rA[0][1]),"v"(rA[0][2]),"v"(rA[0][3]),"v"(rA[0][4]),
                       "v"(rA[1][0]),"v"(rA[1][1]),"v"(rA[1][2]),"v"(rA[1][3]),"v"(rA[1][4]));
    asm volatile("" :: "v"(rA[2][0]),"v"(rA[2][1]),"v"(rA[2][2]),"v"(rA[2][3]),"v"(rA[2][4]),
                       "v"(rB[0][0]),"v"(rB[0][1]),"v"(rB[0][2]),"v"(rB[0][3]),"v"(rB[0][4]),
                       "v"(rB[1][0]),"v"(rB[1][1]),"v"(rB[1][2]),"v"(rB[1][3]),"v"(rB[1][4]));
    asm volatile("" :: "v"(rB[2][0]),"v"(rB[2][1]),"v"(rB[2][2]),"v"(rB[2][3]),"v"(rB[2][4]));

    float aLe=0.f, aLo=0.f, aHe=0.f, aHo=0.f;
#pragma unroll
    for (int p = 0; p < 5; ++p) {
      const float lv  = rl[p];
      const float lhv = (rA[0][p] + sgn * rB[0][p]) * INV_SQRT2;
      const float hlv = (rA[1][p] + sgn * rB[1][p]) * INV_SQRT2;
      const float hhv = (rA[2][p] + sgn * rB[2][p]) * INV_SQRT2;
      const float ce0 = c_qshift[n][9 - 2*p][0], ce1 = c_qshift[n][9 - 2*p][1];
      const float co0 = c_qshift[n][8 - 2*p][0], co1 = c_qshift[n][8 - 2*p][1];
      aLe += ce0 * lv  + ce1 * lhv;
      aLo += co0 * lv  + co1 * lhv;
      aHe += ce0 * hlv + ce1 * hhv;
      aHo += co0 * hlv + co1 * hhv;
    }
    lae[4]=aLe; lao[4]=aLo; hae[4]=aHe; hao[4]=aHo;

    if (ui >= 4) {
      const int s = s0 + ui - 4;
      float o00=0.f, o01=0.f, o10=0.f, o11=0.f;
#pragma unroll
      for (int p = 0; p < 5; ++p) {
        const float f0l = c_qshift[m][9 - 2*p][0], f0h = c_qshift[m][9 - 2*p][1];
        const float f1l = c_qshift[m][8 - 2*p][0], f1h = c_qshift[m][8 - 2*p][1];
        o00 += f0l*lae[4-p] + f0h*hae[4-p];
        o01 += f0l*lao[4-p] + f0h*hao[4-p];
        o10 += f1l*lae[4-p] + f1h*hae[4-p];
        o11 += f1l*lao[4-p] + f1h*hao[4-p];
      }
      float* q = outp + (2*s) * ROWO + (2*t) * C + c;
      q[0]        = o00;
      q[C]        = o01;
      q[ROWO]     = o10;
      q[ROWO + C] = o11;
    }
  }
}

// ---------------------------------------------------------------------------
// Stage 2: TWO-ROWS-PER-PHASE, SEG=16, single 2-row LDS buffer (padded).
// R13 proved: barrier-pinned loads + big VGPR budget (padded LDS) = no spill,
// 2x per-wave throughput. Remaining costs measured: 2 barriers/ROW and SEG=8
// +20% work. This round: stage rows 2j,2j+1 per phase -> barriers per row
// halved (10 phases x 2 for 20 rows), 32 loads in flight (2x MLP), SEG=16
// (work/output 1.5->1.25, FETCH ~154MB). LDS 43.5KB used in 2 halves, padded
// to 49,152B -> 3 blocks/CU -> VGPR budget ~170 >= ~140 needed.
// Window period 5, rows slotted at i%5; phase j computes i0=2j (slot (2jp)%5)
// then i1=2j+1 — output(i0) reads slot (i0-4)%5 BEFORE i1 overwrites it.
// ---------------------------------------------------------------------------
__global__ __launch_bounds__(256, 4) void idtcwt_stage2(
    const float* __restrict__ lo2, const float* __restrict__ highs0,
    float* __restrict__ out)
{
  constexpr int HIN = 256, WIN = 256, C = 3, B = 16;
  constexpr int ROWF  = WIN * C;        // 768 floats per input row
  constexpr int ROWO  = 2 * WIN * C;    // 1536
  constexpr int PLANE = HIN * WIN * C;  // 196608
  constexpr int OPLANE = 512 * 512 * C; // 786432
  constexpr int SEG   = 16;
  constexpr int PITCH = 5;              // float4s per slot (16 arrays + pad)
  constexpr int HALF  = 272 * PITCH;    // 1360 float4 per row-half
  constexpr int LDSV4 = 3072;           // 49,152 B -> 3 blocks/CU, budget ~170

  __shared__ float4 lds4[LDSV4];

  const int tid = threadIdx.x;
  const int jj  = blockIdx.x * 256 + tid;  // 0..767 = (t,c)
  const int c   = jj % 3;
  const int t   = jj / 3;
  const int b   = blockIdx.z;

  const int bandStride = B * PLANE;
  const float* a0  = lo2 + (0 * B + b) * PLANE;           // l00
  const float* a1  = lo2 + (1 * B + b) * PLANE;           // l01
  const float* a2  = lo2 + (2 * B + b) * PLANE;           // l10
  const float* a3  = lo2 + (3 * B + b) * PLANE;           // l11
  const float* h00b0 = highs0 + (0 * 3 * B + b) * PLANE;
  const float* h01b0 = highs0 + (1 * 3 * B + b) * PLANE;
  const float* h10b0 = highs0 + (2 * 3 * B + b) * PLANE;
  const float* h11b0 = highs0 + (3 * 3 * B + b) * PLANE;
  const float* h00b1 = h00b0 + bandStride;
  const float* h01b1 = h01b0 + bandStride;
  const float* h10b1 = h10b0 + bandStride;
  const float* h11b1 = h11b0 + bandStride;
  const float* h00b2 = h00b0 + 2*bandStride;
  const float* h01b2 = h01b0 + 2*bandStride;
  const float* h10b2 = h10b0 + 2*bandStride;
  const float* h11b2 = h11b0 + 2*bandStride;

  // staging source offsets (slot k holds global jj' = 256*blockIdx.x - 6 + k)
  int j1 = jj - 6;   if (j1 < 0)     j1 += ROWF;   // slot tid
  int j2 = jj + 250; if (j2 >= ROWF) j2 -= ROWF;   // slot 256+tid (tid<12)
  const bool halo = (tid < 12);

  // circular window, period 5 (row i -> slot i%5), static after unroll
  float wla0e[5], wla0o[5], wla1e[5], wla1o[5];
  float wha0e[5], wha0o[5], wha1e[5], wha1o[5];
#pragma unroll
  for (int k = 0; k < 5; ++k) {
    wla0e[k]=0.f; wla0o[k]=0.f; wla1e[k]=0.f; wla1o[k]=0.f;
    wha0e[k]=0.f; wha0o[k]=0.f; wha1e[k]=0.f; wha1o[k]=0.f;
  }

  const int s0 = blockIdx.y * SEG;
  float* outb = out + b * OPLANE;

  float4 GA0, GA1, GA2, GA3;                       // prefetch row even
  float4 GAh0 = make_float4(0,0,0,0), GAh1 = GAh0, GAh2 = GAh0, GAh3 = GAh0;
  float4 GB0, GB1, GB2, GB3;                       // prefetch row odd
  float4 GBh0 = make_float4(0,0,0,0), GBh1 = GBh0, GBh2 = GBh0, GBh3 = GBh0;

#define S2_LOADR(I, g0,g1,g2,g3, hh0,hh1,hh2,hh3)                            \
  {                                                                          \
    const int rb_ = ((s0 - 2 + (I)) & (HIN - 1)) * ROWF;                     \
    const int o1_ = rb_ + j1;                                                \
    g0 = make_float4(a0[o1_], a1[o1_], a2[o1_], a3[o1_]);                    \
    g1 = make_float4(h00b0[o1_], h11b0[o1_], h01b0[o1_], h10b0[o1_]);        \
    g2 = make_float4(h00b1[o1_], h11b1[o1_], h01b1[o1_], h10b1[o1_]);        \
    g3 = make_float4(h00b2[o1_], h11b2[o1_], h01b2[o1_], h10b2[o1_]);        \
    if (halo) {                                                              \
      const int o2_ = rb_ + j2;                                              \
      hh0 = make_float4(a0[o2_], a1[o2_], a2[o2_], a3[o2_]);                 \
      hh1 = make_float4(h00b0[o2_], h11b0[o2_], h01b0[o2_], h10b0[o2_]);     \
      hh2 = make_float4(h00b1[o2_], h11b1[o2_], h01b1[o2_], h10b1[o2_]);     \
      hh3 = make_float4(h00b2[o2_], h11b2[o2_], h01b2[o2_], h10b2[o2_]);     \
    }                                                                        \
  }

// pre-butterfly + 0.5-fold, then ds_write_b128 into half HOFF.
#define S2_WRITER(HOFF, g0,g1,g2,g3, hh0,hh1,hh2,hh3)                        \
  {                                                                          \
    float4* w_ = lds4 + (HOFF) + tid * PITCH;                                \
    w_[0] = make_float4(g0.x*0.5f, g0.y*0.5f, g0.z*0.5f, g0.w*0.5f);         \
    w_[1] = make_float4((g1.x+g1.y)*KH, (g1.x-g1.y)*KH,                      \
                        (g1.z+g1.w)*KH, (g1.z-g1.w)*KH);                     \
    w_[2] = make_float4((g2.x+g2.y)*KH, (g2.x-g2.y)*KH,                      \
                        (g2.z+g2.w)*KH, (g2.z-g2.w)*KH);                     \
    w_[3] = make_float4((g3.x+g3.y)*KH, (g3.x-g3.y)*KH,                      \
                        (g3.z+g3.w)*KH, (g3.z-g3.w)*KH);                     \
    if (halo) {                                                              \
      float4* w2_ = lds4 + (HOFF) + (256 + tid) * PITCH;                     \
      w2_[0] = make_float4(hh0.x*0.5f, hh0.y*0.5f, hh0.z*0.5f, hh0.w*0.5f);  \
      w2_[1] = make_float4((hh1.x+hh1.y)*KH, (hh1.x-hh1.y)*KH,               \
                           (hh1.z+hh1.w)*KH, (hh1.z-hh1.w)*KH);              \
      w2_[2] = make_float4((hh2.x+hh2.y)*KH, (hh2.x-hh2.y)*KH,               \
                           (hh2.z+hh2.w)*KH, (hh2.z-hh2.w)*KH);              \
      w2_[3] = make_float4((hh3.x+hh3.y)*KH, (hh3.x-hh3.y)*KH,               \
                           (hh3.z+hh3.w)*KH, (hh3.z-hh3.w)*KH);              \
    }                                                                        \
  }

// column pass of one row from LDS half HOFF into window slot KS (literal),
// then (if IVAL>=4) emit output row IVAL-4. KS and p are compile-time.
#define S2_COL(HOFF, KS, IVAL)                                               \
  {                                                                          \
    float A0e=0.f,A0o=0.f,A1e=0.f,A1o=0.f, H0e=0.f,H0o=0.f,H1e=0.f,H1o=0.f;  \
    _Pragma("unroll")                                                        \
    for (int p = 0; p < 5; ++p) {                                            \
      const float4* qp = lds4 + (HOFF) + (tid + (12 - 3*p)) * PITCH;         \
      const float4 q0 = qp[0], q1 = qp[1], q2 = qp[2], q3 = qp[3];           \
      const float a0e_ = c_first[0][9-2*p][0], a0o_ = c_first[0][8-2*p][0];  \
      const float b0e_ = c_first[0][9-2*p][1], b0o_ = c_first[0][8-2*p][1];  \
      const float a1e_ = c_first[1][9-2*p][0], a1o_ = c_first[1][8-2*p][0];  \
      const float b1e_ = c_first[1][9-2*p][1], b1o_ = c_first[1][8-2*p][1];  \
      A0e += a0e_*q0.x + a1e_*q0.y;   A0o += a0o_*q0.x + a1o_*q0.y;          \
      A1e += a0e_*q0.z + a1e_*q0.w;   A1o += a0o_*q0.z + a1o_*q0.w;          \
      A0e += b0e_*q1.x + b1e_*q1.z;   A0o += b0o_*q1.x + b1o_*q1.z;          \
      A1e += b0e_*q1.w + b1e_*q1.y;   A1o += b0o_*q1.w + b1o_*q1.y;          \
      H0e += a0e_*q2.x + a1e_*q2.z;   H0o += a0o_*q2.x + a1o_*q2.z;          \
      H1e += a0e_*q2.w + a1e_*q2.y;   H1o += a0o_*q2.w + a1o_*q2.y;          \
      H0e += b0e_*q3.x + b1e_*q3.z;   H0o += b0o_*q3.x + b1o_*q3.z;          \
      H1e += b0e_*q3.w + b1e_*q3.y;   H1o += b0o_*q3.w + b1o_*q3.y;          \
    }                                                                        \
    wla0e[KS]=A0e; wla0o[KS]=A0o; wla1e[KS]=A1e; wla1o[KS]=A1o;              \
    wha0e[KS]=H0e; wha0o[KS]=H0o; wha1e[KS]=H1e; wha1o[KS]=H1o;              \
    if ((IVAL) >= 4) {                                                       \
      const int s_ = s0 + (IVAL) - 4;                                        \
      float o00=0.f, o01=0.f, o10=0.f, o11=0.f;                              \
      _Pragma("unroll")                                                      \
      for (int p = 0; p < 5; ++p) {                                          \
        const int kk = ((KS) - p + 5) % 5;                                   \
        const float f00 = c_first[0][9-2*p][0], g00 = c_first[0][9-2*p][1];  \
        const float f01 = c_first[0][8-2*p][0], g01 = c_first[0][8-2*p][1];  \
        const float f10 = c_first[1][9-2*p][0], g10 = c_first[1][9-2*p][1];  \
        const float f11 = c_first[1][8-2*p][0], g11 = c_first[1][8-2*p][1];  \
        o00 += f00*wla0e[kk] + g00*wha0e[kk] + f10*wla1e[kk] + g10*wha1e[kk];\
        o01 += f00*wla0o[kk] + g00*wha0o[kk] + f10*wla1o[kk] + g10*wha1o[kk];\
        o10 += f01*wla0e[kk] + g01*wha0e[kk] + f11*wla1e[kk] + g11*wha1e[kk];\
        o11 += f01*wla0o[kk] + g01*wha0o[kk] + f11*wla1o[kk] + g11*wha1o[kk];\
      }                                                                      \
      float* q_ = outb + (2*s_) * ROWO + (2*t) * C + c;                      \
      q_[0]        = o00;                                                    \
      q_[C]        = o01;                                                    \
      q_[ROWO]     = o10;                                                    \
      q_[ROWO + C] = o11;                                                    \
    }                                                                        \
  }

  // ---- prologue: rows 0,1 -> halves 0,1 ----
  S2_LOADR(0, GA0,GA1,GA2,GA3, GAh0,GAh1,GAh2,GAh3);
  S2_LOADR(1, GB0,GB1,GB2,GB3, GBh0,GBh1,GBh2,GBh3);
  S2_WRITER(0,    GA0,GA1,GA2,GA3, GAh0,GAh1,GAh2,GAh3);
  S2_WRITER(HALF, GB0,GB1,GB2,GB3, GBh0,GBh1,GBh2,GBh3);
  __syncthreads();

#pragma unroll 1
  for (int uo = 0; uo < 2; ++uo) {
#pragma unroll
    for (int jp = 0; jp < 5; ++jp) {
      const int jph = uo * 5 + jp;        // phase 0..9
      const int i0  = 2 * jph;            // even row (slot (2jp)%5, static)
      const int i1  = i0 + 1;             // odd row  (slot (2jp+1)%5)

      if (jph < 9) {                      // prefetch rows i0+2, i1+2
        S2_LOADR(i0 + 2, GA0,GA1,GA2,GA3, GAh0,GAh1,GAh2,GAh3);
        S2_LOADR(i1 + 2, GB0,GB1,GB2,GB3, GBh0,GBh1,GBh2,GBh3);
        __builtin_amdgcn_sched_barrier(0);  // keep load issue at phase top
      }

      // compute both rows (reads both LDS halves), window slots static
      S2_COL(0,    (2*jp) % 5,     i0);
      S2_COL(HALF, (2*jp + 1) % 5, i1);

      __syncthreads();                    // B1: all reads of lds4 complete
      if (jph < 9) {
        S2_WRITER(0,    GA0,GA1,GA2,GA3, GAh0,GAh1,GAh2,GAh3);
        S2_WRITER(HALF, GB0,GB1,GB2,GB3, GBh0,GBh1,GBh2,GBh3);
      }
      __syncthreads();                    // B2: writes visible
    }
  }
#undef S2_LOADR
#undef S2_WRITER
#undef S2_COL
}

extern "C" void kernel_launch(void* const* d_in, const int* in_sizes, int n_in,
                              void* d_out, int out_size, void* d_ws, size_t ws_size,
                              hipStream_t stream) {
  const float* highs0 = (const float*)d_in[0];  // (2,2,3,16,256,256,3)
  const float* highs1 = (const float*)d_in[1];  // (2,2,3,16,128,128,3)
  const float* lows   = (const float*)d_in[2];  // (2,2,16,128,128,3)
  float* out = (float*)d_out;                   // (16,512,512,3)
  float* lo2 = (float*)d_ws;                    // 50.3 MB

  // Stage 1 (R9 form): 8 row segments of 16; 4x16 planes
  dim3 b1(128), g1(3, 8, 64);
  hipLaunchKernelGGL(idtcwt_stage1, g1, b1, 0, stream, lows, highs1, lo2);

  // Stage 2: 16 row segments of 16; 16 batches -> 768 blocks = 3/CU
  dim3 b2(256), g2(3, 16, 16);
  hipLaunchKernelGGL(idtcwt_stage2, g2, b2, 0, stream, lo2, highs0, out);
}

// Round 15
// 107.978 us; speedup vs baseline: 1.2211x; 1.2211x over previous
//
#include <hip/hip_runtime.h>

#define INV_SQRT2 0.70710678118654752440f
#define KH 0.35355339059327376220f   // INV_SQRT2 * 0.5 (output scale folded in)

// Stage-2 (first-stage) filter table as constexpr: compile-time indices after
// unroll -> coefficients fold to immediates; structural zeros kill 20% of FMAs.
constexpr float c_first[2][10][2] = {
  { { 0.00000000000000f,  0.00000000000000f},
    {-0.08838834764832f, -0.01122679215254f},
    { 0.08838834764832f,  0.01122679215254f},
    { 0.69587998903400f,  0.08838834764832f},
    { 0.69587998903400f,  0.08838834764832f},
    { 0.08838834764832f, -0.69587998903400f},
    {-0.08838834764832f,  0.69587998903400f},
    { 0.01122679215254f, -0.08838834764832f},
    { 0.01122679215254f, -0.08838834764832f},
    { 0.00000000000000f,  0.00000000000000f} },
  { { 0.01122679215254f,  0.00000000000000f},
    { 0.01122679215254f,  0.00000000000000f},
    {-0.08838834764832f, -0.08838834764832f},
    { 0.08838834764832f, -0.08838834764832f},
    { 0.69587998903400f,  0.69587998903400f},
    { 0.69587998903400f, -0.69587998903400f},
    { 0.08838834764832f,  0.08838834764832f},
    {-0.08838834764832f,  0.08838834764832f},
    { 0.00000000000000f,  0.01122679215254f},
    { 0.00000000000000f, -0.01122679215254f} }
};

// Stage-1 table stays __constant__: its [n]/[m] indices are runtime-uniform.
__constant__ float c_qshift[2][10][2] = {
  { { 0.03516384f,  0.00000000f},
    { 0.00000000f,  0.00000000f},
    {-0.08832942f, -0.11430184f},
    { 0.23389032f,  0.00000000f},
    { 0.76027237f,  0.58751830f},
    { 0.58751830f, -0.76027237f},
    { 0.00000000f,  0.23389032f},
    {-0.11430184f,  0.08832942f},
    { 0.00000000f,  0.00000000f},
    { 0.00000000f, -0.03516384f} },
  { { 0.00000000f, -0.03516384f},
    { 0.00000000f,  0.00000000f},
    {-0.11430184f,  0.08832942f},
    { 0.00000000f,  0.23389032f},
    { 0.58751830f, -0.76027237f},
    { 0.76027237f,  0.58751830f},
    { 0.23389032f,  0.00000000f},
    {-0.08832942f, -0.11430184f},
    { 0.00000000f,  0.00000000f},
    { 0.03516384f,  0.00000000f} }
};

// ---------------------------------------------------------------------------
// Stage 1: level-2 synthesis (Q-shift) — R9 exact form (proven ~23us):
// SEG=16, launch_bounds(128,3), gather + keep-alive pins.
// ---------------------------------------------------------------------------
__global__ __launch_bounds__(128, 3) void idtcwt_stage1(
    const float* __restrict__ lows, const float* __restrict__ highs1,
    float* __restrict__ lo2)
{
  constexpr int HIN = 128, WIN = 128, C = 3, B = 16;
  constexpr int ROWF  = WIN * C;        // 384 floats per input row
  constexpr int ROWO  = 2 * WIN * C;    // 768 floats per output row
  constexpr int PLANE = HIN * WIN * C;  // 49152
  constexpr int SEG   = 16;

  const int jj = blockIdx.x * 128 + threadIdx.x;  // 0..383 = (t, c)
  const int c  = jj % 3;
  const int t  = jj / 3;                // input column 0..127
  const int z  = blockIdx.z;            // combo*16 + b
  const int combo = z >> 4;
  const int b     = z & 15;
  const int m = combo >> 1, n = combo & 1;

  const float* lo = lows + (combo * B + b) * PLANE;
  const int pa = (m == n) ? 0 : 1;
  const int pb = (m == n) ? 3 : 2;
  const float sgn = (m == 0) ? 1.0f : -1.0f;
  const int bandStride = B * PLANE;     // 786432
  const float* hA = highs1 + (pa * 3 * B + b) * PLANE;
  const float* hB = highs1 + (pb * 3 * B + b) * PLANE;

  int wc3[5];
#pragma unroll
  for (int p = 0; p < 5; ++p) {
    int w = t + 2 - p;
    if (w >= WIN) w -= WIN;
    if (w < 0)  w += WIN;
    wc3[p] = w * C + c;
  }

  float lae[5], lao[5], hae[5], hao[5];
#pragma unroll
  for (int k = 0; k < 5; ++k) { lae[k]=0.f; lao[k]=0.f; hae[k]=0.f; hao[k]=0.f; }

  const int s0 = blockIdx.y * SEG;
  float* outp = lo2 + (combo * B + b) * (4 * PLANE);

#pragma unroll 1
  for (int ui = 0; ui < SEG + 4; ++ui) {
    const int u  = (s0 - 2 + ui) & (HIN - 1);
#pragma unroll
    for (int k = 0; k < 4; ++k) { lae[k]=lae[k+1]; lao[k]=lao[k+1]; hae[k]=hae[k+1]; hao[k]=hao[k+1]; }
    const int rb = u * ROWF;

    float rl[5], rA[3][5], rB[3][5];
#pragma unroll
    for (int p = 0; p < 5; ++p) {
      const int idx = rb + wc3[p];
      rl[p]    = lo[idx];
      rA[0][p] = hA[idx];
      rB[0][p] = hB[idx];
      rA[1][p] = hA[idx +   bandStride];
      rB[1][p] = hB[idx +   bandStride];
      rA[2][p] = hA[idx + 2*bandStride];
      rB[2][p] = hB[idx + 2*bandStride];
    }
    // keep-alive pins: forbid chunking of the 35-load batch
    asm volatile("" :: "v"(rl[0]),"v"(rl[1]),"v"(rl[2]),"v"(rl[3]),"v"(rl[4]),
                       "v"(rA[0][0]),"v"(rA[0][1]),"v"(rA[0][2]),"v"(rA[0][3]),"v"(rA[0][4]),
                       "v"(rA[1][0]),"v"(rA[1][1]),"v"(rA[1][2]),"v"(rA[1][3]),"v"(rA[1][4]));
    asm volatile("" :: "v"(rA[2][0]),"v"(rA[2][1]),"v"(rA[2][2]),"v"(rA[2][3]),"v"(rA[2][4]),
                       "v"(rB[0][0]),"v"(rB[0][1]),"v"(rB[0][2]),"v"(rB[0][3]),"v"(rB[0][4]),
                       "v"(rB[1][0]),"v"(rB[1][1]),"v"(rB[1][2]),"v"(rB[1][3]),"v"(rB[1][4]));
    asm volatile("" :: "v"(rB[2][0]),"v"(rB[2][1]),"v"(rB[2][2]),"v"(rB[2][3]),"v"(rB[2][4]));

    float aLe=0.f, aLo=0.f, aHe=0.f, aHo=0.f;
#pragma unroll
    for (int p = 0; p < 5; ++p) {
      const float lv  = rl[p];
      const float lhv = (rA[0][p] + sgn * rB[0][p]) * INV_SQRT2;
      const float hlv = (rA[1][p] + sgn * rB[1][p]) * INV_SQRT2;
      const float hhv = (rA[2][p] + sgn * rB[2][p]) * INV_SQRT2;
      const float ce0 = c_qshift[n][9 - 2*p][0], ce1 = c_qshift[n][9 - 2*p][1];
      const float co0 = c_qshift[n][8 - 2*p][0], co1 = c_qshift[n][8 - 2*p][1];
      aLe += ce0 * lv  + ce1 * lhv;
      aLo += co0 * lv  + co1 * lhv;
      aHe += ce0 * hlv + ce1 * hhv;
      aHo += co0 * hlv + co1 * hhv;
    }
    lae[4]=aLe; lao[4]=aLo; hae[4]=aHe; hao[4]=aHo;

    if (ui >= 4) {
      const int s = s0 + ui - 4;
      float o00=0.f, o01=0.f, o10=0.f, o11=0.f;
#pragma unroll
      for (int p = 0; p < 5; ++p) {
        const float f0l = c_qshift[m][9 - 2*p][0], f0h = c_qshift[m][9 - 2*p][1];
        const float f1l = c_qshift[m][8 - 2*p][0], f1h = c_qshift[m][8 - 2*p][1];
        o00 += f0l*lae[4-p] + f0h*hae[4-p];
        o01 += f0l*lao[4-p] + f0h*hao[4-p];
        o10 += f1l*lae[4-p] + f1h*hae[4-p];
        o11 += f1l*lao[4-p] + f1h*hao[4-p];
      }
      float* q = outp + (2*s) * ROWO + (2*t) * C + c;
      q[0]        = o00;
      q[C]        = o01;
      q[ROWO]     = o10;
      q[ROWO + C] = o11;
    }
  }
}

// ---------------------------------------------------------------------------
// Stage 2: R13 structure with SEG=16 — the single-variable experiment R14
// skipped. One row per phase, ONE prefetch register set (R14's two sets ->
// VGPR 228 -> occupancy collapse), single-buffer LDS + split barriers,
// padded to 49,152 B (3 blocks/CU -> VGPR budget ~170; R13 proved no spill
// at VGPR=108 with the barrier-pinned batch). SEG=16: work/output 1.5->1.25,
// FETCH ~154MB, grid 768 = exactly 3 blocks/CU resident (12 waves/CU).
// Window period 5 (NI=20=4x5), all indices static.
// ---------------------------------------------------------------------------
__global__ __launch_bounds__(256, 4) void idtcwt_stage2(
    const float* __restrict__ lo2, const float* __restrict__ highs0,
    float* __restrict__ out)
{
  constexpr int HIN = 256, WIN = 256, C = 3, B = 16;
  constexpr int ROWF  = WIN * C;        // 768 floats per input row
  constexpr int ROWO  = 2 * WIN * C;    // 1536
  constexpr int PLANE = HIN * WIN * C;  // 196608
  constexpr int OPLANE = 512 * 512 * C; // 786432
  constexpr int SEG   = 16;
  constexpr int NI    = SEG + 4;        // 20 row phases
  constexpr int PITCH = 5;              // float4s per slot (16 arrays + pad)
  constexpr int LDSV4 = 3072;           // 49,152 B -> 3 blk/CU, budget ~170

  __shared__ float4 lds4[LDSV4];        // 21,760 B used; padded for budget

  const int tid = threadIdx.x;
  const int jj  = blockIdx.x * 256 + tid;  // 0..767 = (t,c)
  const int c   = jj % 3;
  const int t   = jj / 3;
  const int b   = blockIdx.z;

  const int bandStride = B * PLANE;
  const float* a0  = lo2 + (0 * B + b) * PLANE;           // l00
  const float* a1  = lo2 + (1 * B + b) * PLANE;           // l01
  const float* a2  = lo2 + (2 * B + b) * PLANE;           // l10
  const float* a3  = lo2 + (3 * B + b) * PLANE;           // l11
  const float* h00b0 = highs0 + (0 * 3 * B + b) * PLANE;
  const float* h01b0 = highs0 + (1 * 3 * B + b) * PLANE;
  const float* h10b0 = highs0 + (2 * 3 * B + b) * PLANE;
  const float* h11b0 = highs0 + (3 * 3 * B + b) * PLANE;
  const float* h00b1 = h00b0 + bandStride;
  const float* h01b1 = h01b0 + bandStride;
  const float* h10b1 = h10b0 + bandStride;
  const float* h11b1 = h11b0 + bandStride;
  const float* h00b2 = h00b0 + 2*bandStride;
  const float* h01b2 = h01b0 + 2*bandStride;
  const float* h10b2 = h10b0 + 2*bandStride;
  const float* h11b2 = h11b0 + 2*bandStride;

  // staging source offsets (slot k holds global jj' = 256*blockIdx.x - 6 + k)
  int j1 = jj - 6;   if (j1 < 0)     j1 += ROWF;   // slot tid
  int j2 = jj + 250; if (j2 >= ROWF) j2 -= ROWF;   // slot 256+tid (tid<12)
  const bool halo = (tid < 12);

  // circular window, period 5 (row i -> slot i%5), static after unroll
  float wla0e[5], wla0o[5], wla1e[5], wla1o[5];
  float wha0e[5], wha0o[5], wha1e[5], wha1o[5];
#pragma unroll
  for (int k = 0; k < 5; ++k) {
    wla0e[k]=0.f; wla0o[k]=0.f; wla1e[k]=0.f; wla1o[k]=0.f;
    wha0e[k]=0.f; wha0o[k]=0.f; wha1e[k]=0.f; wha1o[k]=0.f;
  }

  const int s0 = blockIdx.y * SEG;
  float* outb = out + b * OPLANE;

  float4 G0, G1, G2, G3;
  float4 Hh0 = make_float4(0.f,0.f,0.f,0.f), Hh1 = Hh0, Hh2 = Hh0, Hh3 = Hh0;

#define S2_LOAD(I)                                                           \
  {                                                                          \
    const int rb_ = ((s0 - 2 + (I)) & (HIN - 1)) * ROWF;                     \
    const int o1_ = rb_ + j1;                                                \
    G0 = make_float4(a0[o1_], a1[o1_], a2[o1_], a3[o1_]);                    \
    G1 = make_float4(h00b0[o1_], h11b0[o1_], h01b0[o1_], h10b0[o1_]);        \
    G2 = make_float4(h00b1[o1_], h11b1[o1_], h01b1[o1_], h10b1[o1_]);        \
    G3 = make_float4(h00b2[o1_], h11b2[o1_], h01b2[o1_], h10b2[o1_]);        \
    if (halo) {                                                              \
      const int o2_ = rb_ + j2;                                              \
      Hh0 = make_float4(a0[o2_], a1[o2_], a2[o2_], a3[o2_]);                 \
      Hh1 = make_float4(h00b0[o2_], h11b0[o2_], h01b0[o2_], h10b0[o2_]);     \
      Hh2 = make_float4(h00b1[o2_], h11b1[o2_], h01b1[o2_], h10b1[o2_]);     \
      Hh3 = make_float4(h00b2[o2_], h11b2[o2_], h01b2[o2_], h10b2[o2_]);     \
    }                                                                        \
  }

// pre-butterfly + 0.5-fold, then 4x ds_write_b128.
#define S2_WRITE()                                                           \
  {                                                                          \
    float4* w_ = lds4 + tid * PITCH;                                         \
    w_[0] = make_float4(G0.x*0.5f, G0.y*0.5f, G0.z*0.5f, G0.w*0.5f);         \
    w_[1] = make_float4((G1.x+G1.y)*KH, (G1.x-G1.y)*KH,                      \
                        (G1.z+G1.w)*KH, (G1.z-G1.w)*KH);                     \
    w_[2] = make_float4((G2.x+G2.y)*KH, (G2.x-G2.y)*KH,                      \
                        (G2.z+G2.w)*KH, (G2.z-G2.w)*KH);                     \
    w_[3] = make_float4((G3.x+G3.y)*KH, (G3.x-G3.y)*KH,                      \
                        (G3.z+G3.w)*KH, (G3.z-G3.w)*KH);                     \
    if (halo) {                                                              \
      float4* w2_ = lds4 + (256 + tid) * PITCH;                              \
      w2_[0] = make_float4(Hh0.x*0.5f, Hh0.y*0.5f, Hh0.z*0.5f, Hh0.w*0.5f);  \
      w2_[1] = make_float4((Hh1.x+Hh1.y)*KH, (Hh1.x-Hh1.y)*KH,               \
                           (Hh1.z+Hh1.w)*KH, (Hh1.z-Hh1.w)*KH);              \
      w2_[2] = make_float4((Hh2.x+Hh2.y)*KH, (Hh2.x-Hh2.y)*KH,               \
                           (Hh2.z+Hh2.w)*KH, (Hh2.z-Hh2.w)*KH);              \
      w2_[3] = make_float4((Hh3.x+Hh3.y)*KH, (Hh3.x-Hh3.y)*KH,               \
                           (Hh3.z+Hh3.w)*KH, (Hh3.z-Hh3.w)*KH);              \
    }                                                                        \
  }

  // ---- prologue: stage row 0 ----
  S2_LOAD(0);
  S2_WRITE();
  __syncthreads();

#pragma unroll 1
  for (int uo = 0; uo < 4; ++uo) {
#pragma unroll
    for (int k = 0; k < 5; ++k) {
      const int i = uo * 5 + k;           // window slot = k (static; i%5==k)

      if (i < NI - 1) {
        S2_LOAD(i + 1);
        __builtin_amdgcn_sched_barrier(0);  // keep load issue at phase top
      }

      // ---- column pass from lds4: taps at slot tid + 12 - 3p ----
      float A0e=0.f,A0o=0.f,A1e=0.f,A1o=0.f, H0e=0.f,H0o=0.f,H1e=0.f,H1o=0.f;
#pragma unroll
      for (int p = 0; p < 5; ++p) {
        const float4* qp = lds4 + (tid + (12 - 3*p)) * PITCH;
        const float4 q0 = qp[0], q1 = qp[1], q2 = qp[2], q3 = qp[3];
        const float a0e = c_first[0][9-2*p][0], a0o = c_first[0][8-2*p][0];
        const float b0e = c_first[0][9-2*p][1], b0o = c_first[0][8-2*p][1];
        const float a1e = c_first[1][9-2*p][0], a1o = c_first[1][8-2*p][0];
        const float b1e = c_first[1][9-2*p][1], b1o = c_first[1][8-2*p][1];
        // lo2 terms (q0 = 0.5*(v00,v01,v10,v11))
        A0e += a0e*q0.x + a1e*q0.y;   A0o += a0o*q0.x + a1o*q0.y;
        A1e += a0e*q0.z + a1e*q0.w;   A1o += a0o*q0.z + a1o*q0.w;
        // LH band: q1 = (s1,d1,s2,d2)
        A0e += b0e*q1.x + b1e*q1.z;   A0o += b0o*q1.x + b1o*q1.z;
        A1e += b0e*q1.w + b1e*q1.y;   A1o += b0o*q1.w + b1o*q1.y;
        // HL band
        H0e += a0e*q2.x + a1e*q2.z;   H0o += a0o*q2.x + a1o*q2.z;
        H1e += a0e*q2.w + a1e*q2.y;   H1o += a0o*q2.w + a1o*q2.y;
        // HH band
        H0e += b0e*q3.x + b1e*q3.z;   H0o += b0o*q3.x + b1o*q3.z;
        H1e += b0e*q3.w + b1e*q3.y;   H1o += b0o*q3.w + b1o*q3.y;
      }
      wla0e[k]=A0e; wla0o[k]=A0o; wla1e[k]=A1e; wla1o[k]=A1o;
      wha0e[k]=H0e; wha0o[k]=H0o; wha1e[k]=H1e; wha1o[k]=H1o;

      if (i >= 4) {
        const int s = s0 + i - 4;
        float o00=0.f, o01=0.f, o10=0.f, o11=0.f;
#pragma unroll
        for (int p = 0; p < 5; ++p) {
          const int kk = (k - p + 5) % 5;   // static
          const float f00 = c_first[0][9-2*p][0], g00 = c_first[0][9-2*p][1];
          const float f01 = c_first[0][8-2*p][0], g01 = c_first[0][8-2*p][1];
          const float f10 = c_first[1][9-2*p][0], g10 = c_first[1][9-2*p][1];
          const float f11 = c_first[1][8-2*p][0], g11 = c_first[1][8-2*p][1];
          o00 += f00*wla0e[kk] + g00*wha0e[kk] + f10*wla1e[kk] + g10*wha1e[kk];
          o01 += f00*wla0o[kk] + g00*wha0o[kk] + f10*wla1o[kk] + g10*wha1o[kk];
          o10 += f01*wla0e[kk] + g01*wha0e[kk] + f11*wla1e[kk] + g11*wha1e[kk];
          o11 += f01*wla0o[kk] + g01*wha0o[kk] + f11*wla1o[kk] + g11*wha1o[kk];
        }
        float* q = outb + (2*s) * ROWO + (2*t) * C + c;
        q[0]        = o00;   // 0.5 folded into staging
        q[C]        = o01;
        q[ROWO]     = o10;
        q[ROWO + C] = o11;
      }

      __syncthreads();                    // B1: all reads of lds4 complete
      if (i < NI - 1) {
        S2_WRITE();                       // overwrite with row i+1
      }
      __syncthreads();                    // B2: writes visible
    }
  }
#undef S2_LOAD
#undef S2_WRITE
}

extern "C" void kernel_launch(void* const* d_in, const int* in_sizes, int n_in,
                              void* d_out, int out_size, void* d_ws, size_t ws_size,
                              hipStream_t stream) {
  const float* highs0 = (const float*)d_in[0];  // (2,2,3,16,256,256,3)
  const float* highs1 = (const float*)d_in[1];  // (2,2,3,16,128,128,3)
  const float* lows   = (const float*)d_in[2];  // (2,2,16,128,128,3)
  float* out = (float*)d_out;                   // (16,512,512,3)
  float* lo2 = (float*)d_ws;                    // 50.3 MB

  // Stage 1 (R9 form): 8 row segments of 16; 4x16 planes
  dim3 b1(128), g1(3, 8, 64);
  hipLaunchKernelGGL(idtcwt_stage1, g1, b1, 0, stream, lows, highs1, lo2);

  // Stage 2: 16 row segments of 16; 16 batches -> 768 blocks = 3/CU
  dim3 b2(256), g2(3, 16, 16);
  hipLaunchKernelGGL(idtcwt_stage2, g2, b2, 0, stream, lo2, highs0, out);
}

// Round 18
// 107.895 us; speedup vs baseline: 1.2220x; 1.0008x over previous
//
#include <hip/hip_runtime.h>

#define INV_SQRT2 0.70710678118654752440f
#define KH 0.35355339059327376220f   // INV_SQRT2 * 0.5 (output scale folded in)

// Stage-2 filter table as constexpr: compile-time indices after unroll ->
// coefficients fold to immediates; structural zeros kill 20% of FMAs.
constexpr float c_first[2][10][2] = {
  { { 0.00000000000000f,  0.00000000000000f},
    {-0.08838834764832f, -0.01122679215254f},
    { 0.08838834764832f,  0.01122679215254f},
    { 0.69587998903400f,  0.08838834764832f},
    { 0.69587998903400f,  0.08838834764832f},
    { 0.08838834764832f, -0.69587998903400f},
    {-0.08838834764832f,  0.69587998903400f},
    { 0.01122679215254f, -0.08838834764832f},
    { 0.01122679215254f, -0.08838834764832f},
    { 0.00000000000000f,  0.00000000000000f} },
  { { 0.01122679215254f,  0.00000000000000f},
    { 0.01122679215254f,  0.00000000000000f},
    {-0.08838834764832f, -0.08838834764832f},
    { 0.08838834764832f, -0.08838834764832f},
    { 0.69587998903400f,  0.69587998903400f},
    { 0.69587998903400f, -0.69587998903400f},
    { 0.08838834764832f,  0.08838834764832f},
    {-0.08838834764832f,  0.08838834764832f},
    { 0.00000000000000f,  0.01122679215254f},
    { 0.00000000000000f, -0.01122679215254f} }
};

// Q-shift table, now constexpr: stage1 dispatches a templated body per
// (M,N) combo, so all indices are compile-time -> immediates + zero folding.
constexpr float cq[2][10][2] = {
  { { 0.03516384f,  0.00000000f},
    { 0.00000000f,  0.00000000f},
    {-0.08832942f, -0.11430184f},
    { 0.23389032f,  0.00000000f},
    { 0.76027237f,  0.58751830f},
    { 0.58751830f, -0.76027237f},
    { 0.00000000f,  0.23389032f},
    {-0.11430184f,  0.08832942f},
    { 0.00000000f,  0.00000000f},
    { 0.00000000f, -0.03516384f} },
  { { 0.00000000f, -0.03516384f},
    { 0.00000000f,  0.00000000f},
    {-0.11430184f,  0.08832942f},
    { 0.00000000f,  0.23389032f},
    { 0.58751830f, -0.76027237f},
    { 0.76027237f,  0.58751830f},
    { 0.23389032f,  0.00000000f},
    {-0.08832942f, -0.11430184f},
    { 0.00000000f,  0.00000000f},
    { 0.03516384f,  0.00000000f} }
};

// ---------------------------------------------------------------------------
// Stage 1 body, templated on the (M,N) combo: coefficients fold to immediates
// (q-shift zeros kill ~20% of taps), butterfly sign is a compile-time add/sub,
// INV_SQRT2 folds into the coefficient immediates (saves 15 v_mul/iter).
// Structure unchanged from R9 (gather + keep-alive pins, SEG=16).
// ---------------------------------------------------------------------------
template<int M, int N>
__device__ __forceinline__ void s1_body(
    const float* __restrict__ lows, const float* __restrict__ highs1,
    float* __restrict__ lo2)
{
  constexpr int HIN = 128, WIN = 128, C = 3, B = 16;
  constexpr int ROWF  = WIN * C;        // 384
  constexpr int ROWO  = 2 * WIN * C;    // 768
  constexpr int PLANE = HIN * WIN * C;  // 49152
  constexpr int SEG   = 16;
  constexpr int combo = M * 2 + N;
  constexpr int pa = (M == N) ? 0 : 1;
  constexpr int pb = (M == N) ? 3 : 2;
  constexpr float K = INV_SQRT2;

  const int jj = blockIdx.x * 128 + threadIdx.x;  // 0..383 = (t, c)
  const int c  = jj % 3;
  const int t  = jj / 3;
  const int b  = blockIdx.z & 15;

  const float* lo = lows + (combo * B + b) * PLANE;
  const int bandStride = B * PLANE;
  const float* hA = highs1 + (pa * 3 * B + b) * PLANE;
  const float* hB = highs1 + (pb * 3 * B + b) * PLANE;

  int wc3[5];
#pragma unroll
  for (int p = 0; p < 5; ++p) {
    int w = t + 2 - p;
    if (w >= WIN) w -= WIN;
    if (w < 0)  w += WIN;
    wc3[p] = w * C + c;
  }

  float lae[5], lao[5], hae[5], hao[5];
#pragma unroll
  for (int k = 0; k < 5; ++k) { lae[k]=0.f; lao[k]=0.f; hae[k]=0.f; hao[k]=0.f; }

  const int s0 = blockIdx.y * SEG;
  float* outp = lo2 + (combo * B + b) * (4 * PLANE);

#pragma unroll 1
  for (int ui = 0; ui < SEG + 4; ++ui) {
    const int u  = (s0 - 2 + ui) & (HIN - 1);
#pragma unroll
    for (int k = 0; k < 4; ++k) { lae[k]=lae[k+1]; lao[k]=lao[k+1]; hae[k]=hae[k+1]; hao[k]=hao[k+1]; }
    const int rb = u * ROWF;

    float rl[5], rA[3][5], rB[3][5];
#pragma unroll
    for (int p = 0; p < 5; ++p) {
      const int idx = rb + wc3[p];
      rl[p]    = lo[idx];
      rA[0][p] = hA[idx];
      rB[0][p] = hB[idx];
      rA[1][p] = hA[idx +   bandStride];
      rB[1][p] = hB[idx +   bandStride];
      rA[2][p] = hA[idx + 2*bandStride];
      rB[2][p] = hB[idx + 2*bandStride];
    }
    // keep-alive pins: forbid chunking of the 35-load batch
    asm volatile("" :: "v"(rl[0]),"v"(rl[1]),"v"(rl[2]),"v"(rl[3]),"v"(rl[4]),
                       "v"(rA[0][0]),"v"(rA[0][1]),"v"(rA[0][2]),"v"(rA[0][3]),"v"(rA[0][4]),
                       "v"(rA[1][0]),"v"(rA[1][1]),"v"(rA[1][2]),"v"(rA[1][3]),"v"(rA[1][4]));
    asm volatile("" :: "v"(rA[2][0]),"v"(rA[2][1]),"v"(rA[2][2]),"v"(rA[2][3]),"v"(rA[2][4]),
                       "v"(rB[0][0]),"v"(rB[0][1]),"v"(rB[0][2]),"v"(rB[0][3]),"v"(rB[0][4]),
                       "v"(rB[1][0]),"v"(rB[1][1]),"v"(rB[1][2]),"v"(rB[1][3]),"v"(rB[1][4]));
    asm volatile("" :: "v"(rB[2][0]),"v"(rB[2][1]),"v"(rB[2][2]),"v"(rB[2][3]),"v"(rB[2][4]));

    float aLe=0.f, aLo=0.f, aHe=0.f, aHo=0.f;
#pragma unroll
    for (int p = 0; p < 5; ++p) {
      const float lv  = rl[p];
      // butterflies UNSCALED; K folded into coefficient immediates below
      const float lhv = (M == 0) ? (rA[0][p] + rB[0][p]) : (rA[0][p] - rB[0][p]);
      const float hlv = (M == 0) ? (rA[1][p] + rB[1][p]) : (rA[1][p] - rB[1][p]);
      const float hhv = (M == 0) ? (rA[2][p] + rB[2][p]) : (rA[2][p] - rB[2][p]);
      const float ce0  = cq[N][9-2*p][0];
      const float co0  = cq[N][8-2*p][0];
      const float ce1K = cq[N][9-2*p][1] * K;
      const float co1K = cq[N][8-2*p][1] * K;
      const float ce0K = ce0 * K;
      const float co0K = co0 * K;
      aLe += ce0  * lv  + ce1K * lhv;
      aLo += co0  * lv  + co1K * lhv;
      aHe += ce0K * hlv + ce1K * hhv;
      aHo += co0K * hlv + co1K * hhv;
    }
    lae[4]=aLe; lao[4]=aLo; hae[4]=aHe; hao[4]=aHo;

    if (ui >= 4) {
      const int s = s0 + ui - 4;
      float o00=0.f, o01=0.f, o10=0.f, o11=0.f;
#pragma unroll
      for (int p = 0; p < 5; ++p) {
        const float f0l = cq[M][9-2*p][0], f0h = cq[M][9-2*p][1];
        const float f1l = cq[M][8-2*p][0], f1h = cq[M][8-2*p][1];
        o00 += f0l*lae[4-p] + f0h*hae[4-p];
        o01 += f0l*lao[4-p] + f0h*hao[4-p];
        o10 += f1l*lae[4-p] + f1h*hae[4-p];
        o11 += f1l*lao[4-p] + f1h*hao[4-p];
      }
      float* q = outp + (2*s) * ROWO + (2*t) * C + c;
      q[0]        = o00;
      q[C]        = o01;
      q[ROWO]     = o10;
      q[ROWO + C] = o11;
    }
  }
}

__global__ __launch_bounds__(128, 3) void idtcwt_stage1(
    const float* __restrict__ lows, const float* __restrict__ highs1,
    float* __restrict__ lo2)
{
  const int combo = blockIdx.z >> 4;    // wave-uniform per block
  if      (combo == 0) s1_body<0,0>(lows, highs1, lo2);
  else if (combo == 1) s1_body<0,1>(lows, highs1, lo2);
  else if (combo == 2) s1_body<1,0>(lows, highs1, lo2);
  else                 s1_body<1,1>(lows, highs1, lo2);
}

// ---------------------------------------------------------------------------
// Stage 2: R15 EXACT form (proven passing, ~84us): one row/phase, one
// prefetch set, single-buffer LDS + split barriers, padded to 49,152 B
// (3 blocks/CU -> VGPR budget ~170, no spill at VGPR=68), SEG=16.
// (R16/R17's global_load_lds rewrite failed correctness twice with identical
// error -> DMA line closed; reg-staged ds_write staging retained.)
// ---------------------------------------------------------------------------
__global__ __launch_bounds__(256, 4) void idtcwt_stage2(
    const float* __restrict__ lo2, const float* __restrict__ highs0,
    float* __restrict__ out)
{
  constexpr int HIN = 256, WIN = 256, C = 3, B = 16;
  constexpr int ROWF  = WIN * C;        // 768 floats per input row
  constexpr int ROWO  = 2 * WIN * C;    // 1536
  constexpr int PLANE = HIN * WIN * C;  // 196608
  constexpr int OPLANE = 512 * 512 * C; // 786432
  constexpr int SEG   = 16;
  constexpr int NI    = SEG + 4;        // 20 row phases
  constexpr int PITCH = 5;              // float4s per slot (16 arrays + pad)
  constexpr int LDSV4 = 3072;           // 49,152 B -> 3 blk/CU, budget ~170

  __shared__ float4 lds4[LDSV4];        // 21,760 B used; padded for budget

  const int tid = threadIdx.x;
  const int jj  = blockIdx.x * 256 + tid;  // 0..767 = (t,c)
  const int c   = jj % 3;
  const int t   = jj / 3;
  const int b   = blockIdx.z;

  const int bandStride = B * PLANE;
  const float* a0  = lo2 + (0 * B + b) * PLANE;           // l00
  const float* a1  = lo2 + (1 * B + b) * PLANE;           // l01
  const float* a2  = lo2 + (2 * B + b) * PLANE;           // l10
  const float* a3  = lo2 + (3 * B + b) * PLANE;           // l11
  const float* h00b0 = highs0 + (0 * 3 * B + b) * PLANE;
  const float* h01b0 = highs0 + (1 * 3 * B + b) * PLANE;
  const float* h10b0 = highs0 + (2 * 3 * B + b) * PLANE;
  const float* h11b0 = highs0 + (3 * 3 * B + b) * PLANE;
  const float* h00b1 = h00b0 + bandStride;
  const float* h01b1 = h01b0 + bandStride;
  const float* h10b1 = h10b0 + bandStride;
  const float* h11b1 = h11b0 + bandStride;
  const float* h00b2 = h00b0 + 2*bandStride;
  const float* h01b2 = h01b0 + 2*bandStride;
  const float* h10b2 = h10b0 + 2*bandStride;
  const float* h11b2 = h11b0 + 2*bandStride;

  // staging source offsets (slot k holds global jj' = 256*blockIdx.x - 6 + k)
  int j1 = jj - 6;   if (j1 < 0)     j1 += ROWF;   // slot tid
  int j2 = jj + 250; if (j2 >= ROWF) j2 -= ROWF;   // slot 256+tid (tid<12)
  const bool halo = (tid < 12);

  // circular window, period 5 (row i -> slot i%5), static after unroll
  float wla0e[5], wla0o[5], wla1e[5], wla1o[5];
  float wha0e[5], wha0o[5], wha1e[5], wha1o[5];
#pragma unroll
  for (int k = 0; k < 5; ++k) {
    wla0e[k]=0.f; wla0o[k]=0.f; wla1e[k]=0.f; wla1o[k]=0.f;
    wha0e[k]=0.f; wha0o[k]=0.f; wha1e[k]=0.f; wha1o[k]=0.f;
  }

  const int s0 = blockIdx.y * SEG;
  float* outb = out + b * OPLANE;

  float4 G0, G1, G2, G3;
  float4 Hh0 = make_float4(0.f,0.f,0.f,0.f), Hh1 = Hh0, Hh2 = Hh0, Hh3 = Hh0;

#define S2_LOAD(I)                                                           \
  {                                                                          \
    const int rb_ = ((s0 - 2 + (I)) & (HIN - 1)) * ROWF;                     \
    const int o1_ = rb_ + j1;                                                \
    G0 = make_float4(a0[o1_], a1[o1_], a2[o1_], a3[o1_]);                    \
    G1 = make_float4(h00b0[o1_], h11b0[o1_], h01b0[o1_], h10b0[o1_]);        \
    G2 = make_float4(h00b1[o1_], h11b1[o1_], h01b1[o1_], h10b1[o1_]);        \
    G3 = make_float4(h00b2[o1_], h11b2[o1_], h01b2[o1_], h10b2[o1_]);        \
    if (halo) {                                                              \
      const int o2_ = rb_ + j2;                                              \
      Hh0 = make_float4(a0[o2_], a1[o2_], a2[o2_], a3[o2_]);                 \
      Hh1 = make_float4(h00b0[o2_], h11b0[o2_], h01b0[o2_], h10b0[o2_]);     \
      Hh2 = make_float4(h00b1[o2_], h11b1[o2_], h01b1[o2_], h10b1[o2_]);     \
      Hh3 = make_float4(h00b2[o2_], h11b2[o2_], h01b2[o2_], h10b2[o2_]);     \
    }                                                                        \
  }

// pre-butterfly + 0.5-fold, then 4x ds_write_b128.
#define S2_WRITE()                                                           \
  {                                                                          \
    float4* w_ = lds4 + tid * PITCH;                                         \
    w_[0] = make_float4(G0.x*0.5f, G0.y*0.5f, G0.z*0.5f, G0.w*0.5f);         \
    w_[1] = make_float4((G1.x+G1.y)*KH, (G1.x-G1.y)*KH,                      \
                        (G1.z+G1.w)*KH, (G1.z-G1.w)*KH);                     \
    w_[2] = make_float4((G2.x+G2.y)*KH, (G2.x-G2.y)*KH,                      \
                        (G2.z+G2.w)*KH, (G2.z-G2.w)*KH);                     \
    w_[3] = make_float4((G3.x+G3.y)*KH, (G3.x-G3.y)*KH,                      \
                        (G3.z+G3.w)*KH, (G3.z-G3.w)*KH);                     \
    if (halo) {                                                              \
      float4* w2_ = lds4 + (256 + tid) * PITCH;                              \
      w2_[0] = make_float4(Hh0.x*0.5f, Hh0.y*0.5f, Hh0.z*0.5f, Hh0.w*0.5f);  \
      w2_[1] = make_float4((Hh1.x+Hh1.y)*KH, (Hh1.x-Hh1.y)*KH,               \
                           (Hh1.z+Hh1.w)*KH, (Hh1.z-Hh1.w)*KH);              \
      w2_[2] = make_float4((Hh2.x+Hh2.y)*KH, (Hh2.x-Hh2.y)*KH,               \
                           (Hh2.z+Hh2.w)*KH, (Hh2.z-Hh2.w)*KH);              \
      w2_[3] = make_float4((Hh3.x+Hh3.y)*KH, (Hh3.x-Hh3.y)*KH,               \
                           (Hh3.z+Hh3.w)*KH, (Hh3.z-Hh3.w)*KH);              \
    }                                                                        \
  }

  // ---- prologue: stage row 0 ----
  S2_LOAD(0);
  S2_WRITE();
  __syncthreads();

#pragma unroll 1
  for (int uo = 0; uo < 4; ++uo) {
#pragma unroll
    for (int k = 0; k < 5; ++k) {
      const int i = uo * 5 + k;           // window slot = k (static; i%5==k)

      if (i < NI - 1) {
        S2_LOAD(i + 1);
        __builtin_amdgcn_sched_barrier(0);  // keep load issue at phase top
      }

      // ---- column pass from lds4: taps at slot tid + 12 - 3p ----
      float A0e=0.f,A0o=0.f,A1e=0.f,A1o=0.f, H0e=0.f,H0o=0.f,H1e=0.f,H1o=0.f;
#pragma unroll
      for (int p = 0; p < 5; ++p) {
        const float4* qp = lds4 + (tid + (12 - 3*p)) * PITCH;
        const float4 q0 = qp[0], q1 = qp[1], q2 = qp[2], q3 = qp[3];
        const float a0e = c_first[0][9-2*p][0], a0o = c_first[0][8-2*p][0];
        const float b0e = c_first[0][9-2*p][1], b0o = c_first[0][8-2*p][1];
        const float a1e = c_first[1][9-2*p][0], a1o = c_first[1][8-2*p][0];
        const float b1e = c_first[1][9-2*p][1], b1o = c_first[1][8-2*p][1];
        // lo2 terms (q0 = 0.5*(v00,v01,v10,v11))
        A0e += a0e*q0.x + a1e*q0.y;   A0o += a0o*q0.x + a1o*q0.y;
        A1e += a0e*q0.z + a1e*q0.w;   A1o += a0o*q0.z + a1o*q0.w;
        // LH band: q1 = (s1,d1,s2,d2)
        A0e += b0e*q1.x + b1e*q1.z;   A0o += b0o*q1.x + b1o*q1.z;
        A1e += b0e*q1.w + b1e*q1.y;   A1o += b0o*q1.w + b1o*q1.y;
        // HL band
        H0e += a0e*q2.x + a1e*q2.z;   H0o += a0o*q2.x + a1o*q2.z;
        H1e += a0e*q2.w + a1e*q2.y;   H1o += a0o*q2.w + a1o*q2.y;
        // HH band
        H0e += b0e*q3.x + b1e*q3.z;   H0o += b0o*q3.x + b1o*q3.z;
        H1e += b0e*q3.w + b1e*q3.y;   H1o += b0o*q3.w + b1o*q3.y;
      }
      wla0e[k]=A0e; wla0o[k]=A0o; wla1e[k]=A1e; wla1o[k]=A1o;
      wha0e[k]=H0e; wha0o[k]=H0o; wha1e[k]=H1e; wha1o[k]=H1o;

      if (i >= 4) {
        const int s = s0 + i - 4;
        float o00=0.f, o01=0.f, o10=0.f, o11=0.f;
#pragma unroll
        for (int p = 0; p < 5; ++p) {
          const int kk = (k - p + 5) % 5;   // static
          const float f00 = c_first[0][9-2*p][0], g00 = c_first[0][9-2*p][1];
          const float f01 = c_first[0][8-2*p][0], g01 = c_first[0][8-2*p][1];
          const float f10 = c_first[1][9-2*p][0], g10 = c_first[1][9-2*p][1];
          const float f11 = c_first[1][8-2*p][0], g11 = c_first[1][8-2*p][1];
          o00 += f00*wla0e[kk] + g00*wha0e[kk] + f10*wla1e[kk] + g10*wha1e[kk];
          o01 += f00*wla0o[kk] + g00*wha0o[kk] + f10*wla1o[kk] + g10*wha1o[kk];
          o10 += f01*wla0e[kk] + g01*wha0e[kk] + f11*wla1e[kk] + g11*wha1e[kk];
          o11 += f01*wla0o[kk] + g01*wha0o[kk] + f11*wla1o[kk] + g11*wha1o[kk];
        }
        float* q = outb + (2*s) * ROWO + (2*t) * C + c;
        q[0]        = o00;   // 0.5 folded into staging
        q[C]        = o01;
        q[ROWO]     = o10;
        q[ROWO + C] = o11;
      }

      __syncthreads();                    // B1: all reads of lds4 complete
      if (i < NI - 1) {
        S2_WRITE();                       // overwrite with row i+1
      }
      __syncthreads();                    // B2: writes visible
    }
  }
#undef S2_LOAD
#undef S2_WRITE
}

extern "C" void kernel_launch(void* const* d_in, const int* in_sizes, int n_in,
                              void* d_out, int out_size, void* d_ws, size_t ws_size,
                              hipStream_t stream) {
  const float* highs0 = (const float*)d_in[0];  // (2,2,3,16,256,256,3)
  const float* highs1 = (const float*)d_in[1];  // (2,2,3,16,128,128,3)
  const float* lows   = (const float*)d_in[2];  // (2,2,16,128,128,3)
  float* out = (float*)d_out;                   // (16,512,512,3)
  float* lo2 = (float*)d_ws;                    // 50.3 MB

  // Stage 1: 8 row segments of 16; 4x16 planes (templated body per combo)
  dim3 b1(128), g1(3, 8, 64);
  hipLaunchKernelGGL(idtcwt_stage1, g1, b1, 0, stream, lows, highs1, lo2);

  // Stage 2 (R15 form): 16 row segments of 16; 16 batches -> 768 blocks
  dim3 b2(256), g2(3, 16, 16);
  hipLaunchKernelGGL(idtcwt_stage2, g2, b2, 0, stream, lo2, highs0, out);
}

// Round 19
// 104.544 us; speedup vs baseline: 1.2612x; 1.0321x over previous
//
#include <hip/hip_runtime.h>

#define INV_SQRT2 0.70710678118654752440f
#define KH 0.35355339059327376220f   // INV_SQRT2 * 0.5 (output scale folded in)

// Stage-2 filter table as constexpr: compile-time indices after unroll ->
// coefficients fold to immediates; structural zeros kill 20% of FMAs.
constexpr float c_first[2][10][2] = {
  { { 0.00000000000000f,  0.00000000000000f},
    {-0.08838834764832f, -0.01122679215254f},
    { 0.08838834764832f,  0.01122679215254f},
    { 0.69587998903400f,  0.08838834764832f},
    { 0.69587998903400f,  0.08838834764832f},
    { 0.08838834764832f, -0.69587998903400f},
    {-0.08838834764832f,  0.69587998903400f},
    { 0.01122679215254f, -0.08838834764832f},
    { 0.01122679215254f, -0.08838834764832f},
    { 0.00000000000000f,  0.00000000000000f} },
  { { 0.01122679215254f,  0.00000000000000f},
    { 0.01122679215254f,  0.00000000000000f},
    {-0.08838834764832f, -0.08838834764832f},
    { 0.08838834764832f, -0.08838834764832f},
    { 0.69587998903400f,  0.69587998903400f},
    { 0.69587998903400f, -0.69587998903400f},
    { 0.08838834764832f,  0.08838834764832f},
    {-0.08838834764832f,  0.08838834764832f},
    { 0.00000000000000f,  0.01122679215254f},
    { 0.00000000000000f, -0.01122679215254f} }
};

// Q-shift table, constexpr: stage1 dispatches a templated body per (M,N)
// combo, so all indices are compile-time -> immediates + zero folding.
constexpr float cq[2][10][2] = {
  { { 0.03516384f,  0.00000000f},
    { 0.00000000f,  0.00000000f},
    {-0.08832942f, -0.11430184f},
    { 0.23389032f,  0.00000000f},
    { 0.76027237f,  0.58751830f},
    { 0.58751830f, -0.76027237f},
    { 0.00000000f,  0.23389032f},
    {-0.11430184f,  0.08832942f},
    { 0.00000000f,  0.00000000f},
    { 0.00000000f, -0.03516384f} },
  { { 0.00000000f, -0.03516384f},
    { 0.00000000f,  0.00000000f},
    {-0.11430184f,  0.08832942f},
    { 0.00000000f,  0.23389032f},
    { 0.58751830f, -0.76027237f},
    { 0.76027237f,  0.58751830f},
    { 0.23389032f,  0.00000000f},
    {-0.08832942f, -0.11430184f},
    { 0.00000000f,  0.00000000f},
    { 0.03516384f,  0.00000000f} }
};

// ---------------------------------------------------------------------------
// Stage 1, LDS-row-staged (port of the PROVEN stage2 recipe: reg-staged
// loads -> pre-butterfly -> ds_write; single buffer + split barriers; planar
// [array][slot] pitch 144 dwords, lane-consecutive taps = free 2-way alias).
// Loads/thread-iter: 35 gathers -> 7 coalesced (+12-lane halo). Butterfly
// sign compile-time (template M); K folds into coefficient immediates.
// LDS padded to 27,200 B -> exactly 6 blocks/CU (the grid supply) -> VGPR
// budget ~170, no R11-style allocator spill.
// ---------------------------------------------------------------------------
template<int M, int N>
__device__ __forceinline__ void s1_body(
    const float* __restrict__ lows, const float* __restrict__ highs1,
    float* __restrict__ lo2, float* __restrict__ lds)
{
  constexpr int HIN = 128, WIN = 128, C = 3, B = 16;
  constexpr int ROWF  = WIN * C;        // 384
  constexpr int ROWO  = 2 * WIN * C;    // 768
  constexpr int PLANE = HIN * WIN * C;  // 49152
  constexpr int SEG   = 16;
  constexpr int NI    = SEG + 4;        // 20 row phases
  constexpr int PITCH = 144;            // dwords per array slice (140 used)
  constexpr int combo = M * 2 + N;
  constexpr int pa = (M == N) ? 0 : 1;
  constexpr int pb = (M == N) ? 3 : 2;
  constexpr float K = INV_SQRT2;

  const int tid = threadIdx.x;          // 0..127
  const int jj  = blockIdx.x * 128 + tid;  // 0..383 = (t,c)
  const int c   = jj % 3;
  const int t   = jj / 3;
  const int b   = blockIdx.z & 15;

  const float* lo = lows + (combo * B + b) * PLANE;
  const int bandStride = B * PLANE;
  const float* hA = highs1 + (pa * 3 * B + b) * PLANE;
  const float* hB = highs1 + (pb * 3 * B + b) * PLANE;

  // staging source offsets: slot k holds global jj' = 128*blockIdx.x - 6 + k
  int j1 = jj - 6;   if (j1 < 0)     j1 += ROWF;   // slot tid (full wave)
  int j2 = jj + 122; if (j2 >= ROWF) j2 -= ROWF;   // slot 128+tid (tid<12)
  const bool halo = (tid < 12);

  // circular window, period 5 (row i -> slot i%5), static after unroll
  float lae[5], lao[5], hae[5], hao[5];
#pragma unroll
  for (int k = 0; k < 5; ++k) { lae[k]=0.f; lao[k]=0.f; hae[k]=0.f; hao[k]=0.f; }

  const int s0 = blockIdx.y * SEG;
  float* outp = lo2 + (combo * B + b) * (4 * PLANE);

  float rl, rA0, rB0, rA1, rB1, rA2, rB2;                 // prefetch (main)
  float hl = 0.f, hA0v = 0.f, hB0v = 0.f, hA1v = 0.f,     // prefetch (halo)
        hB1v = 0.f, hA2v = 0.f, hB2v = 0.f;

#define BFY(a_, b_) ((M == 0) ? ((a_) + (b_)) : ((a_) - (b_)))

#define S1_LOAD(I)                                                           \
  {                                                                          \
    const int rb_ = ((s0 - 2 + (I)) & (HIN - 1)) * ROWF;                     \
    rl  = lo[rb_ + j1];                                                      \
    rA0 = hA[rb_ + j1];                rB0 = hB[rb_ + j1];                   \
    rA1 = hA[rb_ + j1 + bandStride];   rB1 = hB[rb_ + j1 + bandStride];      \
    rA2 = hA[rb_ + j1 + 2*bandStride]; rB2 = hB[rb_ + j1 + 2*bandStride];    \
    if (halo) {                                                              \
      hl   = lo[rb_ + j2];                                                   \
      hA0v = hA[rb_ + j2];                hB0v = hB[rb_ + j2];               \
      hA1v = hA[rb_ + j2 + bandStride];   hB1v = hB[rb_ + j2 + bandStride];  \
      hA2v = hA[rb_ + j2 + 2*bandStride]; hB2v = hB[rb_ + j2 + 2*bandStride];\
    }                                                                        \
  }

#define S1_WRITE()                                                           \
  {                                                                          \
    lds[0*PITCH + tid] = rl;                                                 \
    lds[1*PITCH + tid] = BFY(rA0, rB0);                                      \
    lds[2*PITCH + tid] = BFY(rA1, rB1);                                      \
    lds[3*PITCH + tid] = BFY(rA2, rB2);                                      \
    if (halo) {                                                              \
      lds[0*PITCH + 128 + tid] = hl;                                         \
      lds[1*PITCH + 128 + tid] = BFY(hA0v, hB0v);                            \
      lds[2*PITCH + 128 + tid] = BFY(hA1v, hB1v);                            \
      lds[3*PITCH + 128 + tid] = BFY(hA2v, hB2v);                            \
    }                                                                        \
  }

  // ---- prologue: stage row 0 ----
  S1_LOAD(0);
  S1_WRITE();
  __syncthreads();

#pragma unroll 1
  for (int uo = 0; uo < 4; ++uo) {
#pragma unroll
    for (int k = 0; k < 5; ++k) {
      const int i = uo * 5 + k;           // window slot = k (static; i%5==k)

      if (i < NI - 1) {
        S1_LOAD(i + 1);
        __builtin_amdgcn_sched_barrier(0);  // keep load issue at phase top
      }

      // ---- column pass: taps at slot tid + 12 - 3p ----
      float aLe=0.f, aLo=0.f, aHe=0.f, aHo=0.f;
#pragma unroll
      for (int p = 0; p < 5; ++p) {
        const int sl = tid + (12 - 3*p);
        const float lv  = lds[0*PITCH + sl];
        const float lhv = lds[1*PITCH + sl];   // butterflied, unscaled
        const float hlv = lds[2*PITCH + sl];
        const float hhv = lds[3*PITCH + sl];
        const float ce0  = cq[N][9-2*p][0];
        const float co0  = cq[N][8-2*p][0];
        const float ce1K = cq[N][9-2*p][1] * K;
        const float co1K = cq[N][8-2*p][1] * K;
        const float ce0K = ce0 * K;
        const float co0K = co0 * K;
        aLe += ce0  * lv  + ce1K * lhv;
        aLo += co0  * lv  + co1K * lhv;
        aHe += ce0K * hlv + ce1K * hhv;
        aHo += co0K * hlv + co1K * hhv;
      }
      lae[k]=aLe; lao[k]=aLo; hae[k]=aHe; hao[k]=aHo;

      if (i >= 4) {
        const int s = s0 + i - 4;
        float o00=0.f, o01=0.f, o10=0.f, o11=0.f;
#pragma unroll
        for (int p = 0; p < 5; ++p) {
          const int kk = (k - p + 5) % 5;   // static
          const float f0l = cq[M][9-2*p][0], f0h = cq[M][9-2*p][1];
          const float f1l = cq[M][8-2*p][0], f1h = cq[M][8-2*p][1];
          o00 += f0l*lae[kk] + f0h*hae[kk];
          o01 += f0l*lao[kk] + f0h*hao[kk];
          o10 += f1l*lae[kk] + f1h*hae[kk];
          o11 += f1l*lao[kk] + f1h*hao[kk];
        }
        float* q = outp + (2*s) * ROWO + (2*t) * C + c;
        q[0]        = o00;
        q[C]        = o01;
        q[ROWO]     = o10;
        q[ROWO + C] = o11;
      }

      __syncthreads();                    // B1: all reads of lds complete
      if (i < NI - 1) {
        S1_WRITE();                       // overwrite with row i+1
      }
      __syncthreads();                    // B2: writes visible
    }
  }
#undef S1_LOAD
#undef S1_WRITE
#undef BFY
}

__global__ __launch_bounds__(128, 3) void idtcwt_stage1(
    const float* __restrict__ lows, const float* __restrict__ highs1,
    float* __restrict__ lo2)
{
  // 27,200 B (576 dwords used): pads LDS so residency = 6 blocks/CU (the
  // grid supply) -> allocator VGPR budget ~170 (R13/R15 trick, no spill).
  __shared__ float s1lds[6800];
  const int combo = blockIdx.z >> 4;    // wave-uniform per block
  if      (combo == 0) s1_body<0,0>(lows, highs1, lo2, s1lds);
  else if (combo == 1) s1_body<0,1>(lows, highs1, lo2, s1lds);
  else if (combo == 2) s1_body<1,0>(lows, highs1, lo2, s1lds);
  else                 s1_body<1,1>(lows, highs1, lo2, s1lds);
}

// ---------------------------------------------------------------------------
// Stage 2: R15/R18 EXACT form (proven passing, ~84us): one row/phase, one
// prefetch set, single-buffer LDS + split barriers, padded to 49,152 B
// (3 blocks/CU -> VGPR budget ~170, no spill at VGPR=68), SEG=16.
// ---------------------------------------------------------------------------
__global__ __launch_bounds__(256, 4) void idtcwt_stage2(
    const float* __restrict__ lo2, const float* __restrict__ highs0,
    float* __restrict__ out)
{
  constexpr int HIN = 256, WIN = 256, C = 3, B = 16;
  constexpr int ROWF  = WIN * C;        // 768 floats per input row
  constexpr int ROWO  = 2 * WIN * C;    // 1536
  constexpr int PLANE = HIN * WIN * C;  // 196608
  constexpr int OPLANE = 512 * 512 * C; // 786432
  constexpr int SEG   = 16;
  constexpr int NI    = SEG + 4;        // 20 row phases
  constexpr int PITCH = 5;              // float4s per slot (16 arrays + pad)
  constexpr int LDSV4 = 3072;           // 49,152 B -> 3 blk/CU, budget ~170

  __shared__ float4 lds4[LDSV4];        // 21,760 B used; padded for budget

  const int tid = threadIdx.x;
  const int jj  = blockIdx.x * 256 + tid;  // 0..767 = (t,c)
  const int c   = jj % 3;
  const int t   = jj / 3;
  const int b   = blockIdx.z;

  const int bandStride = B * PLANE;
  const float* a0  = lo2 + (0 * B + b) * PLANE;           // l00
  const float* a1  = lo2 + (1 * B + b) * PLANE;           // l01
  const float* a2  = lo2 + (2 * B + b) * PLANE;           // l10
  const float* a3  = lo2 + (3 * B + b) * PLANE;           // l11
  const float* h00b0 = highs0 + (0 * 3 * B + b) * PLANE;
  const float* h01b0 = highs0 + (1 * 3 * B + b) * PLANE;
  const float* h10b0 = highs0 + (2 * 3 * B + b) * PLANE;
  const float* h11b0 = highs0 + (3 * 3 * B + b) * PLANE;
  const float* h00b1 = h00b0 + bandStride;
  const float* h01b1 = h01b0 + bandStride;
  const float* h10b1 = h10b0 + bandStride;
  const float* h11b1 = h11b0 + bandStride;
  const float* h00b2 = h00b0 + 2*bandStride;
  const float* h01b2 = h01b0 + 2*bandStride;
  const float* h10b2 = h10b0 + 2*bandStride;
  const float* h11b2 = h11b0 + 2*bandStride;

  // staging source offsets (slot k holds global jj' = 256*blockIdx.x - 6 + k)
  int j1 = jj - 6;   if (j1 < 0)     j1 += ROWF;   // slot tid
  int j2 = jj + 250; if (j2 >= ROWF) j2 -= ROWF;   // slot 256+tid (tid<12)
  const bool halo = (tid < 12);

  // circular window, period 5 (row i -> slot i%5), static after unroll
  float wla0e[5], wla0o[5], wla1e[5], wla1o[5];
  float wha0e[5], wha0o[5], wha1e[5], wha1o[5];
#pragma unroll
  for (int k = 0; k < 5; ++k) {
    wla0e[k]=0.f; wla0o[k]=0.f; wla1e[k]=0.f; wla1o[k]=0.f;
    wha0e[k]=0.f; wha0o[k]=0.f; wha1e[k]=0.f; wha1o[k]=0.f;
  }

  const int s0 = blockIdx.y * SEG;
  float* outb = out + b * OPLANE;

  float4 G0, G1, G2, G3;
  float4 Hh0 = make_float4(0.f,0.f,0.f,0.f), Hh1 = Hh0, Hh2 = Hh0, Hh3 = Hh0;

#define S2_LOAD(I)                                                           \
  {                                                                          \
    const int rb_ = ((s0 - 2 + (I)) & (HIN - 1)) * ROWF;                     \
    const int o1_ = rb_ + j1;                                                \
    G0 = make_float4(a0[o1_], a1[o1_], a2[o1_], a3[o1_]);                    \
    G1 = make_float4(h00b0[o1_], h11b0[o1_], h01b0[o1_], h10b0[o1_]);        \
    G2 = make_float4(h00b1[o1_], h11b1[o1_], h01b1[o1_], h10b1[o1_]);        \
    G3 = make_float4(h00b2[o1_], h11b2[o1_], h01b2[o1_], h10b2[o1_]);        \
    if (halo) {                                                              \
      const int o2_ = rb_ + j2;                                              \
      Hh0 = make_float4(a0[o2_], a1[o2_], a2[o2_], a3[o2_]);                 \
      Hh1 = make_float4(h00b0[o2_], h11b0[o2_], h01b0[o2_], h10b0[o2_]);     \
      Hh2 = make_float4(h00b1[o2_], h11b1[o2_], h01b1[o2_], h10b1[o2_]);     \
      Hh3 = make_float4(h00b2[o2_], h11b2[o2_], h01b2[o2_], h10b2[o2_]);     \
    }                                                                        \
  }

// pre-butterfly + 0.5-fold, then 4x ds_write_b128.
#define S2_WRITE()                                                           \
  {                                                                          \
    float4* w_ = lds4 + tid * PITCH;                                         \
    w_[0] = make_float4(G0.x*0.5f, G0.y*0.5f, G0.z*0.5f, G0.w*0.5f);         \
    w_[1] = make_float4((G1.x+G1.y)*KH, (G1.x-G1.y)*KH,                      \
                        (G1.z+G1.w)*KH, (G1.z-G1.w)*KH);                     \
    w_[2] = make_float4((G2.x+G2.y)*KH, (G2.x-G2.y)*KH,                      \
                        (G2.z+G2.w)*KH, (G2.z-G2.w)*KH);                     \
    w_[3] = make_float4((G3.x+G3.y)*KH, (G3.x-G3.y)*KH,                      \
                        (G3.z+G3.w)*KH, (G3.z-G3.w)*KH);                     \
    if (halo) {                                                              \
      float4* w2_ = lds4 + (256 + tid) * PITCH;                              \
      w2_[0] = make_float4(Hh0.x*0.5f, Hh0.y*0.5f, Hh0.z*0.5f, Hh0.w*0.5f);  \
      w2_[1] = make_float4((Hh1.x+Hh1.y)*KH, (Hh1.x-Hh1.y)*KH,               \
                           (Hh1.z+Hh1.w)*KH, (Hh1.z-Hh1.w)*KH);              \
      w2_[2] = make_float4((Hh2.x+Hh2.y)*KH, (Hh2.x-Hh2.y)*KH,               \
                           (Hh2.z+Hh2.w)*KH, (Hh2.z-Hh2.w)*KH);              \
      w2_[3] = make_float4((Hh3.x+Hh3.y)*KH, (Hh3.x-Hh3.y)*KH,               \
                           (Hh3.z+Hh3.w)*KH, (Hh3.z-Hh3.w)*KH);              \
    }                                                                        \
  }

  // ---- prologue: stage row 0 ----
  S2_LOAD(0);
  S2_WRITE();
  __syncthreads();

#pragma unroll 1
  for (int uo = 0; uo < 4; ++uo) {
#pragma unroll
    for (int k = 0; k < 5; ++k) {
      const int i = uo * 5 + k;           // window slot = k (static; i%5==k)

      if (i < NI - 1) {
        S2_LOAD(i + 1);
        __builtin_amdgcn_sched_barrier(0);  // keep load issue at phase top
      }

      // ---- column pass from lds4: taps at slot tid + 12 - 3p ----
      float A0e=0.f,A0o=0.f,A1e=0.f,A1o=0.f, H0e=0.f,H0o=0.f,H1e=0.f,H1o=0.f;
#pragma unroll
      for (int p = 0; p < 5; ++p) {
        const float4* qp = lds4 + (tid + (12 - 3*p)) * PITCH;
        const float4 q0 = qp[0], q1 = qp[1], q2 = qp[2], q3 = qp[3];
        const float a0e = c_first[0][9-2*p][0], a0o = c_first[0][8-2*p][0];
        const float b0e = c_first[0][9-2*p][1], b0o = c_first[0][8-2*p][1];
        const float a1e = c_first[1][9-2*p][0], a1o = c_first[1][8-2*p][0];
        const float b1e = c_first[1][9-2*p][1], b1o = c_first[1][8-2*p][1];
        // lo2 terms (q0 = 0.5*(v00,v01,v10,v11))
        A0e += a0e*q0.x + a1e*q0.y;   A0o += a0o*q0.x + a1o*q0.y;
        A1e += a0e*q0.z + a1e*q0.w;   A1o += a0o*q0.z + a1o*q0.w;
        // LH band: q1 = (s1,d1,s2,d2)
        A0e += b0e*q1.x + b1e*q1.z;   A0o += b0o*q1.x + b1o*q1.z;
        A1e += b0e*q1.w + b1e*q1.y;   A1o += b0o*q1.w + b1o*q1.y;
        // HL band
        H0e += a0e*q2.x + a1e*q2.z;   H0o += a0o*q2.x + a1o*q2.z;
        H1e += a0e*q2.w + a1e*q2.y;   H1o += a0o*q2.w + a1o*q2.y;
        // HH band
        H0e += b0e*q3.x + b1e*q3.z;   H0o += b0o*q3.x + b1o*q3.z;
        H1e += b0e*q3.w + b1e*q3.y;   H1o += b0o*q3.w + b1o*q3.y;
      }
      wla0e[k]=A0e; wla0o[k]=A0o; wla1e[k]=A1e; wla1o[k]=A1o;
      wha0e[k]=H0e; wha0o[k]=H0o; wha1e[k]=H1e; wha1o[k]=H1o;

      if (i >= 4) {
        const int s = s0 + i - 4;
        float o00=0.f, o01=0.f, o10=0.f, o11=0.f;
#pragma unroll
        for (int p = 0; p < 5; ++p) {
          const int kk = (k - p + 5) % 5;   // static
          const float f00 = c_first[0][9-2*p][0], g00 = c_first[0][9-2*p][1];
          const float f01 = c_first[0][8-2*p][0], g01 = c_first[0][8-2*p][1];
          const float f10 = c_first[1][9-2*p][0], g10 = c_first[1][9-2*p][1];
          const float f11 = c_first[1][8-2*p][0], g11 = c_first[1][8-2*p][1];
          o00 += f00*wla0e[kk] + g00*wha0e[kk] + f10*wla1e[kk] + g10*wha1e[kk];
          o01 += f00*wla0o[kk] + g00*wha0o[kk] + f10*wla1o[kk] + g10*wha1o[kk];
          o10 += f01*wla0e[kk] + g01*wha0e[kk] + f11*wla1e[kk] + g11*wha1e[kk];
          o11 += f01*wla0o[kk] + g01*wha0o[kk] + f11*wla1o[kk] + g11*wha1o[kk];
        }
        float* q = outb + (2*s) * ROWO + (2*t) * C + c;
        q[0]        = o00;   // 0.5 folded into staging
        q[C]        = o01;
        q[ROWO]     = o10;
        q[ROWO + C] = o11;
      }

      __syncthreads();                    // B1: all reads of lds4 complete
      if (i < NI - 1) {
        S2_WRITE();                       // overwrite with row i+1
      }
      __syncthreads();                    // B2: writes visible
    }
  }
#undef S2_LOAD
#undef S2_WRITE
}

extern "C" void kernel_launch(void* const* d_in, const int* in_sizes, int n_in,
                              void* d_out, int out_size, void* d_ws, size_t ws_size,
                              hipStream_t stream) {
  const float* highs0 = (const float*)d_in[0];  // (2,2,3,16,256,256,3)
  const float* highs1 = (const float*)d_in[1];  // (2,2,3,16,128,128,3)
  const float* lows   = (const float*)d_in[2];  // (2,2,16,128,128,3)
  float* out = (float*)d_out;                   // (16,512,512,3)
  float* lo2 = (float*)d_ws;                    // 50.3 MB

  // Stage 1 (LDS-staged): 3 x-blocks of 128; 8 segments of 16; 4x16 planes
  dim3 b1(128), g1(3, 8, 64);
  hipLaunchKernelGGL(idtcwt_stage1, g1, b1, 0, stream, lows, highs1, lo2);

  // Stage 2 (R15 form): 16 row segments of 16; 16 batches -> 768 blocks
  dim3 b2(256), g2(3, 16, 16);
  hipLaunchKernelGGL(idtcwt_stage2, g2, b2, 0, stream, lo2, highs0, out);
}